// Round 11
// baseline (465.248 us; speedup 1.0000x reference)
//
#include <hip/hip_runtime.h>

typedef _Float16 half_t;
typedef _Float16 half8 __attribute__((ext_vector_type(8)));
typedef _Float16 half4 __attribute__((ext_vector_type(4)));
typedef float floatx4 __attribute__((ext_vector_type(4)));
typedef unsigned int u32;

#define MFMA32(a,b,c) __builtin_amdgcn_mfma_f32_16x16x32_f16(a,b,c,0,0,0)
#define MFMA16(a,b,c) __builtin_amdgcn_mfma_f32_16x16x16f16(a,b,c,0,0,0)

// ws layout (fp16 elements)
#define XPAD_ELEMS (10u*34*34*640)   // NHWC padded x
#define WR_ELEMS   (3u*9*640*640)    // conv weights [proj][co][tap][ci]  (K-major rows)
#define WP_ELEMS   (640u*640)        // proj weight [d][c]
#define QKV_ELEMS  (10u*8*1024*80)   // per projection
#define O_ELEMS    (10u*1024*640)    // attention output [img][n][c]

__device__ __forceinline__ void load16_lds(half_t* lds, const half_t* g) {
  __builtin_amdgcn_global_load_lds((const __attribute__((address_space(1))) u32*)g,
                                   (__attribute__((address_space(3))) u32*)lds,
                                   16, 0, 0);
}

// ---------------- convert x: NCHW fp32 -> padded NHWC fp16 ----------------
__global__ __launch_bounds__(256) void k_convert_x(const float* __restrict__ x,
                                                   half_t* __restrict__ xpad) {
  const int img = blockIdx.x >> 5, y = blockIdx.x & 31;
  const float* src = x + (size_t)img*640*1024 + y*32;
  half_t* dst = xpad + (size_t)img*34*34*640;
  for (int i = threadIdx.x; i < 640*32; i += 256) {
    int xx = i / 640, c = i - xx*640;
    float v = src[(size_t)c*1024 + xx];
    dst[((size_t)(y+1)*34 + xx + 1)*640 + c] = (half_t)v;
  }
}

// ---------------- convert weights (coalesced via LDS transpose) ----------------
__global__ __launch_bounds__(256) void k_convert_w(const float* __restrict__ wq,
                                                   const float* __restrict__ wk,
                                                   const float* __restrict__ wv,
                                                   const float* __restrict__ wp,
                                                   half_t* __restrict__ wr2,
                                                   half_t* __restrict__ wp16) {
  __shared__ half_t tr[9*644];
  const int p = blockIdx.y, row = blockIdx.x;
  if (p < 3) {
    const float* W = (p == 0) ? wq : (p == 1) ? wk : wv;
    const float* src = W + (size_t)row*5760;
    for (int j = threadIdx.x; j < 5760; j += 256) {
      int ci = j / 9, t = j - ci*9;
      tr[t*644 + ci] = (half_t)src[j];
    }
    __syncthreads();
    half_t* dst = wr2 + ((size_t)p*640 + row)*5760;
    for (int i = threadIdx.x; i < 5760; i += 256) {
      int t = i / 640, ci = i - t*640;
      dst[i] = tr[t*644 + ci];
    }
  } else {
    for (int i = threadIdx.x; i < 640; i += 256)
      wp16[(size_t)row*640 + i] = (half_t)wp[(size_t)row*640 + i];
  }
}

// ---------------- conv3x3 implicit GEMM: BM=256 x BN=160, 8 waves,
//   region R(s) = [stage S(s+2) ∥ cluster (9 streamed reads + 20 MFMA)][vmcnt][bar]
//   ring-3 W (stage POST-barrier -> streamed reads race-free), dbuf X ------------
#define TRC(T) (((T)/3)*34 + ((T) - ((T)/3)*3))
#define K0C(T) ((((T)+2)%9)*640 + (((T)+2)/9)*32)

__global__ __launch_bounds__(512) void k_conv(const half_t* __restrict__ xpad,
                                              const half_t* __restrict__ wr2,
                                              const float* __restrict__ bq,
                                              const float* __restrict__ bk,
                                              const float* __restrict__ bv,
                                              half_t* __restrict__ qo,
                                              half_t* __restrict__ ko,
                                              half_t* __restrict__ vo) {
  __shared__ __align__(16) half_t sX[2][1536*8];   // 384 cells x 64B, dbuf (24KB ea)
  __shared__ __align__(16) half_t sW[3][640*8];    // 160 co-rows x 64B, ring-3 (10KB ea)
  const int tid = threadIdx.x;
  const int lane = tid & 63, wv = tid >> 6;
  const int l15 = lane & 15, lq = lane >> 4, lq16 = lq*16;
  // XCD swizzle: 480 = 8 x 60; consecutive wg share (nt,z)
  const int id = blockIdx.x;
  const int wg = (id >> 3) + (id & 7)*60;
  const int mt = wg & 3;
  const int rest = wg >> 2;
  const int nt = rest & 3;
  const int z  = rest >> 2;
  const int proj = z / 10, img = z - proj*10;

  const half_t* xg  = xpad + ((size_t)img*34*34 + (size_t)mt*8*34)*640;
  const half_t* wgp = wr2 + ((size_t)proj*640 + nt*160)*5760;

  int xsrc[3];
#pragma unroll
  for (int kk = 0; kk < 3; ++kk) {
    int unit = kk*512 + tid;
    int row = unit >> 2, sub = unit & 3;
    int ch = sub ^ ((row >> 1) & 3);
    xsrc[kk] = row*640 + ch*8;
  }
  int wsrc0, wsrc1;
  { int row = tid >> 2, sub = tid & 3;
    int ch = sub ^ ((row >> 1) & 3);
    wsrc0 = row*5760 + ch*8; }
  { int unit = 512 + tid;
    int row = unit >> 2, sub = unit & 3;
    int ch = sub ^ ((row >> 1) & 3);
    wsrc1 = row*5760 + ch*8; }

  const int wm = wv >> 1, wn = wv & 1;
  int arow0[4];
#pragma unroll
  for (int fr = 0; fr < 4; ++fr) {
    int p = wm*64 + fr*16 + l15;
    arow0[fr] = (p >> 5)*34 + (p & 31);
  }
  int bbase;
  { int r = wn*80 + l15;
    bbase = r*64 + (lq16 ^ (((r >> 1) & 3) << 4)); }   // +fc*1024 per fc

  // prologue (region R(-1)): X(0), S(0)->slot0, S(1)->slot1
#pragma unroll
  for (int kk = 0; kk < 3; ++kk)
    load16_lds(sX[0] + (size_t)(kk*512 + wv*64)*8, xg + xsrc[kk]);
  load16_lds(sW[0] + (size_t)(wv*64)*8, wgp + wsrc0);
  if (wv < 2) load16_lds(sW[0] + (size_t)(512 + wv*64)*8, wgp + wsrc1);
  load16_lds(sW[1] + (size_t)(wv*64)*8, wgp + wsrc0 + 640);
  if (wv < 2) load16_lds(sW[1] + (size_t)(512 + wv*64)*8, wgp + wsrc1 + 640);
  // B(0): drain X(0)+S(0), leave S(1)
  if (wv < 2) asm volatile("s_waitcnt vmcnt(2)" ::: "memory");
  else        asm volatile("s_waitcnt vmcnt(1)" ::: "memory");
  asm volatile("s_barrier" ::: "memory");

  floatx4 acc[4][5] = {};

  // Region R(s), s = 9g+T:
  //   [stage S(s+2) (+X(g+1) at T==6)] [cluster: 9 streamed ds_reads + 20 MFMA]
  //   [vmcnt(VMW)] [s_barrier]  = B(s+1)
  // VMW=1: leave newest W stage (2|1).  VMW=2: leave newest W + X (5|4).
  // VMW=0: drain all (tail).
#define STEP1(T, DOW, K0E, DOX, VMW)                                               \
  do {                                                                             \
    if (DOW) {                                                                     \
      load16_lds(sW[((T)+2)%3] + (size_t)(wv*64)*8, wgp + wsrc0 + (K0E));          \
      if (wv < 2)                                                                  \
        load16_lds(sW[((T)+2)%3] + (size_t)(512 + wv*64)*8, wgp + wsrc1 + (K0E));  \
    }                                                                              \
    if (DOX) {                                                                     \
      _Pragma("unroll")                                                            \
      for (int kk = 0; kk < 3; ++kk)                                               \
        load16_lds(sxw + (size_t)(kk*512 + wv*64)*8, xg + xsrc[kk] + (g+1)*32);    \
    }                                                                              \
    __builtin_amdgcn_s_setprio(1);                                                 \
    { const char* sXc = (const char*)sxr;                                          \
      const char* sWc = (const char*)(sW[(T)%3]);                                  \
      half8 Aw0 = *(const half8*)(sWc + bbase);                                    \
      half8 Aw1 = *(const half8*)(sWc + bbase + 1024);                             \
      int r0 = arow0[0] + TRC(T);                                                  \
      half8 Av0 = *(const half8*)(sXc + r0*64 + (lq16 ^ (((r0>>1)&3)<<4)));        \
      half8 Aw2 = *(const half8*)(sWc + bbase + 2048);                             \
      int r1 = arow0[1] + TRC(T);                                                  \
      half8 Av1 = *(const half8*)(sXc + r1*64 + (lq16 ^ (((r1>>1)&3)<<4)));        \
      acc[0][0] = MFMA32(Av0, Aw0, acc[0][0]);                                     \
      half8 Aw3 = *(const half8*)(sWc + bbase + 3072);                             \
      acc[0][1] = MFMA32(Av0, Aw1, acc[0][1]);                                     \
      int r2 = arow0[2] + TRC(T);                                                  \
      half8 Av2 = *(const half8*)(sXc + r2*64 + (lq16 ^ (((r2>>1)&3)<<4)));        \
      acc[0][2] = MFMA32(Av0, Aw2, acc[0][2]);                                     \
      half8 Aw4 = *(const half8*)(sWc + bbase + 4096);                             \
      acc[1][0] = MFMA32(Av1, Aw0, acc[1][0]);                                     \
      int r3 = arow0[3] + TRC(T);                                                  \
      half8 Av3 = *(const half8*)(sXc + r3*64 + (lq16 ^ (((r3>>1)&3)<<4)));        \
      acc[0][3] = MFMA32(Av0, Aw3, acc[0][3]);                                     \
      acc[0][4] = MFMA32(Av0, Aw4, acc[0][4]);                                     \
      acc[1][1] = MFMA32(Av1, Aw1, acc[1][1]);                                     \
      acc[1][2] = MFMA32(Av1, Aw2, acc[1][2]);                                     \
      acc[1][3] = MFMA32(Av1, Aw3, acc[1][3]);                                     \
      acc[1][4] = MFMA32(Av1, Aw4, acc[1][4]);                                     \
      acc[2][0] = MFMA32(Av2, Aw0, acc[2][0]);                                     \
      acc[2][1] = MFMA32(Av2, Aw1, acc[2][1]);                                     \
      acc[2][2] = MFMA32(Av2, Aw2, acc[2][2]);                                     \
      acc[2][3] = MFMA32(Av2, Aw3, acc[2][3]);                                     \
      acc[2][4] = MFMA32(Av2, Aw4, acc[2][4]);                                     \
      acc[3][0] = MFMA32(Av3, Aw0, acc[3][0]);                                     \
      acc[3][1] = MFMA32(Av3, Aw1, acc[3][1]);                                     \
      acc[3][2] = MFMA32(Av3, Aw2, acc[3][2]);                                     \
      acc[3][3] = MFMA32(Av3, Aw3, acc[3][3]);                                     \
      acc[3][4] = MFMA32(Av3, Aw4, acc[3][4]);                                     \
    }                                                                              \
    __builtin_amdgcn_s_setprio(0);                                                 \
    if ((VMW) == 2) {                                                              \
      if (wv < 2) asm volatile("s_waitcnt vmcnt(5)" ::: "memory");                 \
      else        asm volatile("s_waitcnt vmcnt(4)" ::: "memory");                 \
    } else if ((VMW) == 1) {                                                       \
      if (wv < 2) asm volatile("s_waitcnt vmcnt(2)" ::: "memory");                 \
      else        asm volatile("s_waitcnt vmcnt(1)" ::: "memory");                 \
    } else {                                                                       \
      asm volatile("s_waitcnt vmcnt(0)" ::: "memory");                             \
    }                                                                              \
    asm volatile("s_barrier" ::: "memory");                                        \
  } while (0)

  for (int g = 0; g < 19; ++g) {
    half_t* sxr = sX[g & 1];
    half_t* sxw = sX[(g + 1) & 1];
    STEP1(0, 1, K0C(0) + g*32, 0, 1);
    STEP1(1, 1, K0C(1) + g*32, 0, 1);
    STEP1(2, 1, K0C(2) + g*32, 0, 1);
    STEP1(3, 1, K0C(3) + g*32, 0, 1);
    STEP1(4, 1, K0C(4) + g*32, 0, 1);
    STEP1(5, 1, K0C(5) + g*32, 0, 1);
    STEP1(6, 1, K0C(6) + g*32, 1, 2);   // stage X(g+1); B(t7): leave W+X
    STEP1(7, 1, K0C(7) + g*32, 0, 2);   // B(t8): leave W+X
    STEP1(8, 1, K0C(8) + g*32, 0, 1);   // B(g+1,t0): drains X
  }
  {
    const int g = 19;
    half_t* sxr = sX[1];
    half_t* sxw = sX[0];   // unused
    (void)sxw;
    STEP1(0, 1, K0C(0) + 19*32, 0, 1);
    STEP1(1, 1, K0C(1) + 19*32, 0, 1);
    STEP1(2, 1, K0C(2) + 19*32, 0, 1);
    STEP1(3, 1, K0C(3) + 19*32, 0, 1);
    STEP1(4, 1, K0C(4) + 19*32, 0, 1);
    STEP1(5, 1, K0C(5) + 19*32, 0, 1);
    STEP1(6, 1, K0C(6) + 19*32, 0, 1);  // stages S(179), the last
    STEP1(7, 0, 0, 0, 0);               // B(179): drain S(179)
    STEP1(8, 0, 0, 0, 0);
    (void)g;
  }
#undef STEP1

  const float* bias = (proj == 0) ? bq : (proj == 1) ? bk : bv;
#pragma unroll
  for (int fc = 0; fc < 5; ++fc) {
    int co = nt*160 + wn*80 + fc*16 + l15;
    float bb = bias[co];
    int hh = 2*nt + wn;            // co/80 (fc*16+l15 < 80)
    int d  = fc*16 + l15;
#pragma unroll
    for (int fr = 0; fr < 4; ++fr)
#pragma unroll
      for (int j = 0; j < 4; ++j) {
        int n = mt*256 + wm*64 + fr*16 + lq*4 + j;
        float val = acc[fr][fc][j] + bb;
        if (proj == 0)      qo[((size_t)(img*8 + hh)*1024 + n)*80 + d] = (half_t)(val * 0.11180339887498949f);
        else if (proj == 1) ko[((size_t)(img*8 + hh)*1024 + n)*80 + d] = (half_t)val;
        else                vo[((size_t)(img*8 + hh)*80 + d)*1024 + n] = (half_t)val;
      }
  }
}

// ---------------- flash attention: QBLK=128, KVBLK=64, hd=80,
//                  K/V double-buffered, Q hoisted to regs, 2 barriers/kt ------
__global__ __launch_bounds__(256) void k_attn(const half_t* __restrict__ qg_,
                                              const half_t* __restrict__ kg_,
                                              const half_t* __restrict__ vg_,
                                              half_t* __restrict__ og_) {
  __shared__ __align__(16) half_t sQ[128*80];
  __shared__ __align__(16) half_t sK[2][64*80];
  __shared__ __align__(16) half_t sV[2][80*64];
  __shared__ __align__(16) half_t sP[128*64];
  const int tid = threadIdx.x, lane = tid & 63, wv = tid >> 6;
  const int l15 = lane & 15, lq = lane >> 4;
  const int id = blockIdx.x;
  const int wgb = (id >> 3) + (id & 7)*80;
  const int qt = wgb & 7, gh = wgb >> 3;
  const half_t* qg = qg_ + ((size_t)gh*1024 + qt*128)*80;
  const half_t* kg = kg_ + (size_t)gh*1024*80;
  const half_t* vg = vg_ + (size_t)gh*80*1024;

#define STAGE_KV(kt, buf) do {                                                \
    _Pragma("unroll")                                                         \
    for (int kk = 0; kk < 3; ++kk) {                                          \
      int c = kk*256 + tid;                                                   \
      if (c < 640) {                                                          \
        int row = c / 10, cw = c - row*10;                                    \
        load16_lds(sK[buf] + (size_t)(kk*256 + wv*64)*8,                      \
                   kg + ((size_t)(kt)*64 + row)*80 + cw*8);                   \
      }                                                                       \
    }                                                                         \
    _Pragma("unroll")                                                         \
    for (int kk = 0; kk < 3; ++kk) {                                          \
      int c = kk*256 + tid;                                                   \
      if (c < 640) {                                                          \
        load16_lds(sV[buf] + (size_t)(kk*256 + wv*64)*8,                      \
                   vg + (size_t)(c >> 3)*1024 + (kt)*64 + (c & 7)*8);         \
      }                                                                       \
    }                                                                         \
  } while (0)

#pragma unroll
  for (int kk = 0; kk < 5; ++kk)
    load16_lds(sQ + (size_t)(kk*256 + wv*64)*8, qg + (size_t)(kk*256 + tid)*8);
  STAGE_KV(0, 0);
  asm volatile("s_waitcnt vmcnt(0)" ::: "memory");
  __builtin_amdgcn_s_barrier();
  __builtin_amdgcn_sched_barrier(0);

  half8 qa0[2], qa1[2]; half4 qa2[2];
  {
    const char* sQb = (const char*)sQ;
#pragma unroll
    for (int fr = 0; fr < 2; ++fr) {
      int r = wv*32 + fr*16 + l15;
      qa0[fr] = *(const half8*)(sQb + r*160 + lq*16);
      qa1[fr] = *(const half8*)(sQb + r*160 + 64 + lq*16);
      qa2[fr] = *(const half4*)(sQb + r*160 + 128 + lq*8);
    }
  }

  float mrow[2][4], lrow[2][4];
  floatx4 oacc[2][5] = {};
#pragma unroll
  for (int fr = 0; fr < 2; ++fr)
#pragma unroll
    for (int j = 0; j < 4; ++j) { mrow[fr][j] = -1e30f; lrow[fr][j] = 0.f; }

  for (int kt = 0; kt < 16; ++kt) {
    const int cur = kt & 1;
    if (kt < 15) STAGE_KV(kt + 1, cur ^ 1);

    const char* sKb = (const char*)sK[cur];
    floatx4 s[2][4];
#pragma unroll
    for (int fc = 0; fc < 4; ++fc) {
      int key = fc*16 + l15;
      half8 kb0 = *(const half8*)(sKb + key*160 + lq*16);
      half8 kb1 = *(const half8*)(sKb + key*160 + 64 + lq*16);
      half4 kb2 = *(const half4*)(sKb + key*160 + 128 + lq*8);
#pragma unroll
      for (int fr = 0; fr < 2; ++fr) {
        floatx4 t = {0.f, 0.f, 0.f, 0.f};
        t = MFMA16(qa2[fr], kb2, t);
        t = MFMA32(qa0[fr], kb0, t);
        t = MFMA32(qa1[fr], kb1, t);
        s[fr][fc] = t;
      }
    }

    float corr[2][4], psum[2][4];
#pragma unroll
    for (int fr = 0; fr < 2; ++fr)
#pragma unroll
      for (int j = 0; j < 4; ++j) {
        float mx = fmaxf(fmaxf(s[fr][0][j], s[fr][1][j]), fmaxf(s[fr][2][j], s[fr][3][j]));
        mx = fmaxf(mx, __shfl_xor(mx, 1));
        mx = fmaxf(mx, __shfl_xor(mx, 2));
        mx = fmaxf(mx, __shfl_xor(mx, 4));
        mx = fmaxf(mx, __shfl_xor(mx, 8));
        float mn = fmaxf(mrow[fr][j], mx);
        corr[fr][j] = __expf(mrow[fr][j] - mn);
        mrow[fr][j] = mn;
        psum[fr][j] = 0.f;
      }
#pragma unroll
    for (int fc = 0; fc < 4; ++fc)
#pragma unroll
      for (int fr = 0; fr < 2; ++fr)
#pragma unroll
        for (int j = 0; j < 4; ++j) {
          float p = __expf(s[fr][fc][j] - mrow[fr][j]);
          psum[fr][j] += p;
          sP[(size_t)(wv*32 + fr*16 + lq*4 + j)*64 + fc*16 + l15] = (half_t)p;
        }
#pragma unroll
    for (int fr = 0; fr < 2; ++fr)
#pragma unroll
      for (int j = 0; j < 4; ++j) {
        float t2 = psum[fr][j];
        t2 += __shfl_xor(t2, 1);
        t2 += __shfl_xor(t2, 2);
        t2 += __shfl_xor(t2, 4);
        t2 += __shfl_xor(t2, 8);
        lrow[fr][j] = lrow[fr][j]*corr[fr][j] + t2;
      }
#pragma unroll
    for (int fr = 0; fr < 2; ++fr)
#pragma unroll
      for (int fc = 0; fc < 5; ++fc)
#pragma unroll
        for (int j = 0; j < 4; ++j)
          oacc[fr][fc][j] *= corr[fr][j];

    asm volatile("s_waitcnt lgkmcnt(0)" ::: "memory");
    __builtin_amdgcn_s_barrier();
    __builtin_amdgcn_sched_barrier(0);

    const char* sPb = (const char*)sP;
    const char* sVb = (const char*)sV[cur];
    half8 pa[2][2];
#pragma unroll
    for (int fr = 0; fr < 2; ++fr) {
      int r = wv*32 + fr*16 + l15;
#pragma unroll
      for (int ks = 0; ks < 2; ++ks)
        pa[fr][ks] = *(const half8*)(sPb + r*128 + ks*64 + lq*16);
    }
#pragma unroll
    for (int fc = 0; fc < 5; ++fc)
#pragma unroll
      for (int ks = 0; ks < 2; ++ks) {
        half8 vb = *(const half8*)(sVb + (fc*16 + l15)*128 + ks*64 + lq*16);
#pragma unroll
        for (int fr = 0; fr < 2; ++fr)
          oacc[fr][fc] = MFMA32(pa[fr][ks], vb, oacc[fr][fc]);
      }

    asm volatile("s_waitcnt vmcnt(0) lgkmcnt(0)" ::: "memory");
    __builtin_amdgcn_s_barrier();
    __builtin_amdgcn_sched_barrier(0);
  }
#undef STAGE_KV

  const int img = gh >> 3, hh = gh & 7;
  half_t* og = og_ + ((size_t)img*1024 + qt*128)*640 + hh*80;
#pragma unroll
  for (int fr = 0; fr < 2; ++fr)
#pragma unroll
    for (int j = 0; j < 4; ++j) {
      int n = wv*32 + fr*16 + lq*4 + j;
      float inv = 1.f / lrow[fr][j];
#pragma unroll
      for (int fc = 0; fc < 5; ++fc)
        og[(size_t)n*640 + fc*16 + l15] = (half_t)(oacc[fr][fc][j] * inv);
    }
}

// ---------------- output projection GEMM (+bias), writes fp32 d_out ----------------
__global__ __launch_bounds__(256) void k_proj(const half_t* __restrict__ oa,
                                              const half_t* __restrict__ wp,
                                              const float* __restrict__ bp,
                                              float* __restrict__ out) {
  __shared__ __align__(16) half_t sA[128*32];
  __shared__ __align__(16) half_t sB[128*32];
  const int tid = threadIdx.x, lane = tid & 63, wv = tid >> 6;
  const int l15 = lane & 15, lq = lane >> 4;
  const int mt = blockIdx.x, nt = blockIdx.y, img = blockIdx.z;
  const int bb = img / 5, mm = img - bb*5;
  const half_t* ag = oa + ((size_t)img*1024 + mt*128)*640;
  const half_t* bg = wp + (size_t)nt*128*640;
  const int wrow = (wv >> 1)*64, wcol = (wv & 1)*64;
  floatx4 acc[4][4] = {};
  for (int g = 0; g < 20; ++g) {
    __syncthreads();
#pragma unroll
    for (int kk = 0; kk < 2; ++kk) {
      int c = kk*256 + tid;
      load16_lds(sA + (size_t)(kk*256 + wv*64)*8, ag + (size_t)(c >> 2)*640 + g*32 + (c & 3)*8);
      load16_lds(sB + (size_t)(kk*256 + wv*64)*8, bg + (size_t)(c >> 2)*640 + g*32 + (c & 3)*8);
    }
    __syncthreads();
    const char* sAb = (const char*)sA;
    const char* sBb = (const char*)sB;
    half8 av[4], bw[4];
#pragma unroll
    for (int fr = 0; fr < 4; ++fr) av[fr] = *(const half8*)(sAb + (wrow + fr*16 + l15)*64 + lq*16);
#pragma unroll
    for (int fc = 0; fc < 4; ++fc) bw[fc] = *(const half8*)(sBb + (wcol + fc*16 + l15)*64 + lq*16);
#pragma unroll
    for (int fr = 0; fr < 4; ++fr)
#pragma unroll
      for (int fc = 0; fc < 4; ++fc)
        acc[fr][fc] = MFMA32(av[fr], bw[fc], acc[fr][fc]);
  }
  float* og = out + ((size_t)bb*1024 + mt*128)*3200 + mm*640 + nt*128;
#pragma unroll
  for (int fc = 0; fc < 4; ++fc) {
    float bias = bp[nt*128 + wcol + fc*16 + l15];
#pragma unroll
    for (int fr = 0; fr < 4; ++fr)
#pragma unroll
      for (int j = 0; j < 4; ++j)
        og[(size_t)(wrow + fr*16 + lq*4 + j)*3200 + wcol + fc*16 + l15] = acc[fr][fc][j] + bias;
  }
}

extern "C" void kernel_launch(void* const* d_in, const int* in_sizes, int n_in,
                              void* d_out, int out_size, void* d_ws, size_t ws_size,
                              hipStream_t stream) {
  const float* x  = (const float*)d_in[0];
  const float* wq = (const float*)d_in[1];
  const float* bq = (const float*)d_in[2];
  const float* wk = (const float*)d_in[3];
  const float* bk = (const float*)d_in[4];
  const float* wv = (const float*)d_in[5];
  const float* bv = (const float*)d_in[6];
  const float* wp = (const float*)d_in[7];
  const float* bp = (const float*)d_in[8];
  float* out = (float*)d_out;

  half_t* xpad = (half_t*)d_ws;
  half_t* wr2  = xpad + XPAD_ELEMS;
  half_t* wp16 = wr2 + WR_ELEMS;
  half_t* q    = wp16 + WP_ELEMS;
  half_t* k    = q + QKV_ELEMS;
  half_t* v    = k + QKV_ELEMS;
  half_t* oa   = v + QKV_ELEMS;

  (void)hipMemsetAsync(xpad, 0, (size_t)XPAD_ELEMS*sizeof(half_t), stream);
  k_convert_x<<<320, 256, 0, stream>>>(x, xpad);
  k_convert_w<<<dim3(640, 4), 256, 0, stream>>>(wq, wk, wv, wp, wr2, wp16);
  k_conv<<<480, 512, 0, stream>>>(xpad, wr2, bq, bk, bv, q, k, v);
  k_attn<<<640, 256, 0, stream>>>(q, k, v, oa);
  k_proj<<<dim3(8, 5, 10), 256, 0, stream>>>(oa, wp16, bp, out);
}

// Round 12
// 373.767 us; speedup vs baseline: 1.2448x; 1.2448x over previous
//
#include <hip/hip_runtime.h>

typedef _Float16 half_t;
typedef _Float16 half8 __attribute__((ext_vector_type(8)));
typedef _Float16 half4 __attribute__((ext_vector_type(4)));
typedef float floatx4 __attribute__((ext_vector_type(4)));
typedef unsigned int u32;

#define MFMA32(a,b,c) __builtin_amdgcn_mfma_f32_16x16x32_f16(a,b,c,0,0,0)
#define MFMA16(a,b,c) __builtin_amdgcn_mfma_f32_16x16x16f16(a,b,c,0,0,0)

// ws layout (fp16 elements)
#define XPAD_ELEMS (10u*34*34*640)   // NHWC padded x
#define WR_ELEMS   (3u*9*640*640)    // conv weights [proj][co][tap][ci]  (K-major rows)
#define WP_ELEMS   (640u*640)        // proj weight [d][c]
#define QKV_ELEMS  (10u*8*1024*80)   // per projection
#define O_ELEMS    (10u*1024*640)    // attention output [img][n][c]

__device__ __forceinline__ void load16_lds(half_t* lds, const half_t* g) {
  __builtin_amdgcn_global_load_lds((const __attribute__((address_space(1))) u32*)g,
                                   (__attribute__((address_space(3))) u32*)lds,
                                   16, 0, 0);
}

// ---------------- convert x: NCHW fp32 -> padded NHWC fp16 (LDS transpose) ------
__global__ __launch_bounds__(256) void k_convert_x(const float* __restrict__ x,
                                                   half_t* __restrict__ xpad) {
  __shared__ half_t tr[32*644];     // [xx][c], pad 644 (write stride 322w = 2 mod 32)
  const int img = blockIdx.x >> 5, y = blockIdx.x & 31;
  const float* src = x + (size_t)img*640*1024 + y*32;
  half_t* dst = xpad + ((size_t)img*34*34 + (size_t)(y+1)*34 + 1)*640;
  for (int i = threadIdx.x; i < 640*32; i += 256) {
    int xx = i & 31, c = i >> 5;
    tr[xx*644 + c] = (half_t)src[(size_t)c*1024 + xx];   // coalesced read
  }
  __syncthreads();
  for (int xx = 0; xx < 32; ++xx)
    for (int c = threadIdx.x; c < 640; c += 256)
      dst[(size_t)xx*640 + c] = tr[xx*644 + c];          // coalesced write
}

// ---------------- convert weights (coalesced via LDS transpose) ----------------
__global__ __launch_bounds__(256) void k_convert_w(const float* __restrict__ wq,
                                                   const float* __restrict__ wk,
                                                   const float* __restrict__ wv,
                                                   const float* __restrict__ wp,
                                                   half_t* __restrict__ wr2,
                                                   half_t* __restrict__ wp16) {
  __shared__ half_t tr[9*644];
  const int p = blockIdx.y, row = blockIdx.x;
  if (p < 3) {
    const float* W = (p == 0) ? wq : (p == 1) ? wk : wv;
    const float* src = W + (size_t)row*5760;
    for (int j = threadIdx.x; j < 5760; j += 256) {
      int ci = j / 9, t = j - ci*9;
      tr[t*644 + ci] = (half_t)src[j];
    }
    __syncthreads();
    half_t* dst = wr2 + ((size_t)p*640 + row)*5760;
    for (int i = threadIdx.x; i < 5760; i += 256) {
      int t = i / 640, ci = i - t*640;
      dst[i] = tr[t*644 + ci];
    }
  } else {
    for (int i = threadIdx.x; i < 640; i += 256)
      wp16[(size_t)row*640 + i] = (half_t)wp[(size_t)row*640 + i];
  }
}

// ---------------- conv3x3 implicit GEMM: BM=256 x BN=160, 8 waves,
//   SINGLE barrier per K-step: [reads+stage][vmcnt N][lgkm 0][bar][MFMA ∥ X-stream]
//   ring-3 W (2-ahead), dbuf X (staged at t6), swizzled, counted vmcnt (R10) ----
#define TRC(T) (((T)/3)*34 + ((T) - ((T)/3)*3))
#define K0C(T) ((((T)+2)%9)*640 + (((T)+2)/9)*32)

__global__ __launch_bounds__(512) void k_conv(const half_t* __restrict__ xpad,
                                              const half_t* __restrict__ wr2,
                                              const float* __restrict__ bq,
                                              const float* __restrict__ bk,
                                              const float* __restrict__ bv,
                                              half_t* __restrict__ qo,
                                              half_t* __restrict__ ko,
                                              half_t* __restrict__ vo) {
  __shared__ __align__(16) half_t sX[2][1536*8];   // 384 cells x 64B, dbuf (24KB ea)
  __shared__ __align__(16) half_t sW[3][640*8];    // 160 co-rows x 64B, ring-3 (10KB ea)
  const int tid = threadIdx.x;
  const int lane = tid & 63, wv = tid >> 6;
  const int l15 = lane & 15, lq = lane >> 4, lq16 = lq*16;
  const int id = blockIdx.x;
  const int wg = (id >> 3) + (id & 7)*60;
  const int mt = wg & 3;
  const int rest = wg >> 2;
  const int nt = rest & 3;
  const int z  = rest >> 2;
  const int proj = z / 10, img = z - proj*10;

  const half_t* xg  = xpad + ((size_t)img*34*34 + (size_t)mt*8*34)*640;
  const half_t* wgp = wr2 + ((size_t)proj*640 + nt*160)*5760;

  int xsrc[3];
#pragma unroll
  for (int kk = 0; kk < 3; ++kk) {
    int unit = kk*512 + tid;
    int row = unit >> 2, sub = unit & 3;
    int ch = sub ^ ((row >> 1) & 3);
    xsrc[kk] = row*640 + ch*8;
  }
  int wsrc0, wsrc1;
  { int row = tid >> 2, sub = tid & 3;
    int ch = sub ^ ((row >> 1) & 3);
    wsrc0 = row*5760 + ch*8; }
  { int unit = 512 + tid;
    int row = unit >> 2, sub = unit & 3;
    int ch = sub ^ ((row >> 1) & 3);
    wsrc1 = row*5760 + ch*8; }

  const int wm = wv >> 1, wn = wv & 1;
  int arow0[4];
#pragma unroll
  for (int fr = 0; fr < 4; ++fr) {
    int p = wm*64 + fr*16 + l15;
    arow0[fr] = (p >> 5)*34 + (p & 31);
  }
  int bbase;
  { int r = wn*80 + l15;
    bbase = r*64 + (lq16 ^ (((r >> 1) & 3) << 4)); }   // +fc*1024 per fc

  // prologue: X(0), W(0)->slot0, W(1)->slot1; wait X(0)+W(0) (leave W(1)); barrier
#pragma unroll
  for (int kk = 0; kk < 3; ++kk)
    load16_lds(sX[0] + (size_t)(kk*512 + wv*64)*8, xg + xsrc[kk]);
  load16_lds(sW[0] + (size_t)(wv*64)*8, wgp + wsrc0);
  if (wv < 2) load16_lds(sW[0] + (size_t)(512 + wv*64)*8, wgp + wsrc1);
  load16_lds(sW[1] + (size_t)(wv*64)*8, wgp + wsrc0 + 640);
  if (wv < 2) load16_lds(sW[1] + (size_t)(512 + wv*64)*8, wgp + wsrc1 + 640);
  if (wv < 2) asm volatile("s_waitcnt vmcnt(2)" ::: "memory");
  else        asm volatile("s_waitcnt vmcnt(1)" ::: "memory");
  asm volatile("s_barrier" ::: "memory");

  floatx4 acc[4][5] = {};

#define STEP1(T, DOW, K0E, DOX, VMW)                                               \
  do {                                                                             \
    half8 Av0, Aw0, Aw1, Aw2, Aw3, Aw4;                                            \
    { const char* sXc = (const char*)sxr;                                          \
      const char* sWc = (const char*)(sW[(T)%3]);                                  \
      int r0 = arow0[0] + TRC(T);                                                  \
      Av0 = *(const half8*)(sXc + r0*64 + (lq16 ^ (((r0>>1)&3)<<4)));              \
      Aw0 = *(const half8*)(sWc + bbase);                                          \
      Aw1 = *(const half8*)(sWc + bbase + 1024);                                   \
      Aw2 = *(const half8*)(sWc + bbase + 2048);                                   \
      Aw3 = *(const half8*)(sWc + bbase + 3072);                                   \
      Aw4 = *(const half8*)(sWc + bbase + 4096); }                                 \
    if (DOW) {                                                                     \
      load16_lds(sW[((T)+2)%3] + (size_t)(wv*64)*8, wgp + wsrc0 + (K0E));          \
      if (wv < 2)                                                                  \
        load16_lds(sW[((T)+2)%3] + (size_t)(512 + wv*64)*8, wgp + wsrc1 + (K0E));  \
    }                                                                              \
    if (DOX) {                                                                     \
      _Pragma("unroll")                                                            \
      for (int kk = 0; kk < 3; ++kk)                                               \
        load16_lds(sxw + (size_t)(kk*512 + wv*64)*8, xg + xsrc[kk] + (g+1)*32);    \
    }                                                                              \
    if ((VMW) == 2) {                                                              \
      if (wv < 2) asm volatile("s_waitcnt vmcnt(5)" ::: "memory");                 \
      else        asm volatile("s_waitcnt vmcnt(4)" ::: "memory");                 \
    } else if ((VMW) == 1) {                                                       \
      if (wv < 2) asm volatile("s_waitcnt vmcnt(2)" ::: "memory");                 \
      else        asm volatile("s_waitcnt vmcnt(1)" ::: "memory");                 \
    } else {                                                                       \
      asm volatile("s_waitcnt vmcnt(0)" ::: "memory");                             \
    }                                                                              \
    asm volatile("s_waitcnt lgkmcnt(0)" ::: "memory");                             \
    asm volatile("s_barrier" ::: "memory");                                        \
    __builtin_amdgcn_sched_barrier(0);                                             \
    __builtin_amdgcn_s_setprio(1);                                                 \
    { const char* sXc = (const char*)sxr;                                          \
      int r1 = arow0[1] + TRC(T);                                                  \
      half8 Av1 = *(const half8*)(sXc + r1*64 + (lq16 ^ (((r1>>1)&3)<<4)));        \
      acc[0][0] = MFMA32(Av0, Aw0, acc[0][0]);                                     \
      acc[0][1] = MFMA32(Av0, Aw1, acc[0][1]);                                     \
      acc[0][2] = MFMA32(Av0, Aw2, acc[0][2]);                                     \
      int r2 = arow0[2] + TRC(T);                                                  \
      half8 Av2 = *(const half8*)(sXc + r2*64 + (lq16 ^ (((r2>>1)&3)<<4)));        \
      acc[0][3] = MFMA32(Av0, Aw3, acc[0][3]);                                     \
      acc[0][4] = MFMA32(Av0, Aw4, acc[0][4]);                                     \
      int r3 = arow0[3] + TRC(T);                                                  \
      half8 Av3 = *(const half8*)(sXc + r3*64 + (lq16 ^ (((r3>>1)&3)<<4)));        \
      acc[1][0] = MFMA32(Av1, Aw0, acc[1][0]);                                     \
      acc[1][1] = MFMA32(Av1, Aw1, acc[1][1]);                                     \
      acc[1][2] = MFMA32(Av1, Aw2, acc[1][2]);                                     \
      acc[1][3] = MFMA32(Av1, Aw3, acc[1][3]);                                     \
      acc[1][4] = MFMA32(Av1, Aw4, acc[1][4]);                                     \
      acc[2][0] = MFMA32(Av2, Aw0, acc[2][0]);                                     \
      acc[2][1] = MFMA32(Av2, Aw1, acc[2][1]);                                     \
      acc[2][2] = MFMA32(Av2, Aw2, acc[2][2]);                                     \
      acc[2][3] = MFMA32(Av2, Aw3, acc[2][3]);                                     \
      acc[2][4] = MFMA32(Av2, Aw4, acc[2][4]);                                     \
      acc[3][0] = MFMA32(Av3, Aw0, acc[3][0]);                                     \
      acc[3][1] = MFMA32(Av3, Aw1, acc[3][1]);                                     \
      acc[3][2] = MFMA32(Av3, Aw2, acc[3][2]);                                     \
      acc[3][3] = MFMA32(Av3, Aw3, acc[3][3]);                                     \
      acc[3][4] = MFMA32(Av3, Aw4, acc[3][4]);                                     \
    }                                                                              \
    __builtin_amdgcn_s_setprio(0);                                                 \
  } while (0)

  for (int g = 0; g < 19; ++g) {
    half_t* sxr = sX[g & 1];
    half_t* sxw = sX[(g + 1) & 1];
    STEP1(0, 1, K0C(0) + g*32, 0, 1);
    STEP1(1, 1, K0C(1) + g*32, 0, 1);
    STEP1(2, 1, K0C(2) + g*32, 0, 1);
    STEP1(3, 1, K0C(3) + g*32, 0, 1);
    STEP1(4, 1, K0C(4) + g*32, 0, 1);
    STEP1(5, 1, K0C(5) + g*32, 0, 1);
    STEP1(6, 1, K0C(6) + g*32, 1, 2);   // + stage X(g+1)
    STEP1(7, 1, K0C(7) + g*32, 0, 2);
    STEP1(8, 1, K0C(8) + g*32, 0, 1);   // forces X(g+1) complete
  }
  {
    const int g = 19;
    half_t* sxr = sX[1];
    half_t* sxw = sX[0];   // unused
    (void)sxw;
    STEP1(0, 1, K0C(0) + 19*32, 0, 1);
    STEP1(1, 1, K0C(1) + 19*32, 0, 1);
    STEP1(2, 1, K0C(2) + 19*32, 0, 1);
    STEP1(3, 1, K0C(3) + 19*32, 0, 1);
    STEP1(4, 1, K0C(4) + 19*32, 0, 1);
    STEP1(5, 1, K0C(5) + 19*32, 0, 1);
    STEP1(6, 1, K0C(6) + 19*32, 0, 1);  // stages W(179), the last
    STEP1(7, 0, 0, 0, 0);
    STEP1(8, 0, 0, 0, 0);
    (void)g;
  }
#undef STEP1

  const float* bias = (proj == 0) ? bq : (proj == 1) ? bk : bv;
#pragma unroll
  for (int fc = 0; fc < 5; ++fc) {
    int co = nt*160 + wn*80 + fc*16 + l15;
    float bb = bias[co];
    int hh = 2*nt + wn;
    int d  = fc*16 + l15;
#pragma unroll
    for (int fr = 0; fr < 4; ++fr)
#pragma unroll
      for (int j = 0; j < 4; ++j) {
        int n = mt*256 + wm*64 + fr*16 + lq*4 + j;
        float val = acc[fr][fc][j] + bb;
        if (proj == 0)      qo[((size_t)(img*8 + hh)*1024 + n)*80 + d] = (half_t)(val * 0.11180339887498949f);
        else if (proj == 1) ko[((size_t)(img*8 + hh)*1024 + n)*80 + d] = (half_t)val;
        else                vo[((size_t)(img*8 + hh)*80 + d)*1024 + n] = (half_t)val;
      }
  }
}

// ---------------- flash attention: QBLK=128, KVBLK=64, hd=80,
//        K/V double-buffered, Q direct global->regs, 2 barriers/kt -------------
__global__ __launch_bounds__(256) void k_attn(const half_t* __restrict__ qg_,
                                              const half_t* __restrict__ kg_,
                                              const half_t* __restrict__ vg_,
                                              half_t* __restrict__ og_) {
  __shared__ __align__(16) half_t sK[2][64*80];
  __shared__ __align__(16) half_t sV[2][80*64];
  __shared__ __align__(16) half_t sP[128*64];
  const int tid = threadIdx.x, lane = tid & 63, wv = tid >> 6;
  const int l15 = lane & 15, lq = lane >> 4;
  const int id = blockIdx.x;
  const int wgb = (id >> 3) + (id & 7)*80;
  const int qt = wgb & 7, gh = wgb >> 3;
  const half_t* qg = qg_ + ((size_t)gh*1024 + qt*128)*80;
  const half_t* kg = kg_ + (size_t)gh*1024*80;
  const half_t* vg = vg_ + (size_t)gh*80*1024;

#define STAGE_KV(kt, buf) do {                                                \
    _Pragma("unroll")                                                         \
    for (int kk = 0; kk < 3; ++kk) {                                          \
      int c = kk*256 + tid;                                                   \
      if (c < 640) {                                                          \
        int row = c / 10, cw = c - row*10;                                    \
        load16_lds(sK[buf] + (size_t)(kk*256 + wv*64)*8,                      \
                   kg + ((size_t)(kt)*64 + row)*80 + cw*8);                   \
      }                                                                       \
    }                                                                         \
    _Pragma("unroll")                                                         \
    for (int kk = 0; kk < 3; ++kk) {                                          \
      int c = kk*256 + tid;                                                   \
      if (c < 640) {                                                          \
        load16_lds(sV[buf] + (size_t)(kk*256 + wv*64)*8,                      \
                   vg + (size_t)(c >> 3)*1024 + (kt)*64 + (c & 7)*8);         \
      }                                                                       \
    }                                                                         \
  } while (0)

  // Q fragments straight from global (per-lane 16B/8B chunks, 16B/8B aligned)
  half8 qa0[2], qa1[2]; half4 qa2[2];
#pragma unroll
  for (int fr = 0; fr < 2; ++fr) {
    int r = wv*32 + fr*16 + l15;
    qa0[fr] = *(const half8*)(qg + (size_t)r*80 + lq*8);
    qa1[fr] = *(const half8*)(qg + (size_t)r*80 + 32 + lq*8);
    qa2[fr] = *(const half4*)(qg + (size_t)r*80 + 64 + lq*4);
  }
  STAGE_KV(0, 0);
  asm volatile("s_waitcnt vmcnt(0)" ::: "memory");
  __builtin_amdgcn_s_barrier();
  __builtin_amdgcn_sched_barrier(0);

  float mrow[2][4], lrow[2][4];
  floatx4 oacc[2][5] = {};
#pragma unroll
  for (int fr = 0; fr < 2; ++fr)
#pragma unroll
    for (int j = 0; j < 4; ++j) { mrow[fr][j] = -1e30f; lrow[fr][j] = 0.f; }

  for (int kt = 0; kt < 16; ++kt) {
    const int cur = kt & 1;
    if (kt < 15) STAGE_KV(kt + 1, cur ^ 1);

    const char* sKb = (const char*)sK[cur];
    floatx4 s[2][4];
#pragma unroll
    for (int fc = 0; fc < 4; ++fc) {
      int key = fc*16 + l15;
      half8 kb0 = *(const half8*)(sKb + key*160 + lq*16);
      half8 kb1 = *(const half8*)(sKb + key*160 + 64 + lq*16);
      half4 kb2 = *(const half4*)(sKb + key*160 + 128 + lq*8);
#pragma unroll
      for (int fr = 0; fr < 2; ++fr) {
        floatx4 t = {0.f, 0.f, 0.f, 0.f};
        t = MFMA16(qa2[fr], kb2, t);
        t = MFMA32(qa0[fr], kb0, t);
        t = MFMA32(qa1[fr], kb1, t);
        s[fr][fc] = t;
      }
    }

    float corr[2][4], psum[2][4];
#pragma unroll
    for (int fr = 0; fr < 2; ++fr)
#pragma unroll
      for (int j = 0; j < 4; ++j) {
        float mx = fmaxf(fmaxf(s[fr][0][j], s[fr][1][j]), fmaxf(s[fr][2][j], s[fr][3][j]));
        mx = fmaxf(mx, __shfl_xor(mx, 1));
        mx = fmaxf(mx, __shfl_xor(mx, 2));
        mx = fmaxf(mx, __shfl_xor(mx, 4));
        mx = fmaxf(mx, __shfl_xor(mx, 8));
        float mn = fmaxf(mrow[fr][j], mx);
        corr[fr][j] = __expf(mrow[fr][j] - mn);
        mrow[fr][j] = mn;
        psum[fr][j] = 0.f;
      }
#pragma unroll
    for (int fc = 0; fc < 4; ++fc)
#pragma unroll
      for (int fr = 0; fr < 2; ++fr)
#pragma unroll
        for (int j = 0; j < 4; ++j) {
          float p = __expf(s[fr][fc][j] - mrow[fr][j]);
          psum[fr][j] += p;
          sP[(size_t)(wv*32 + fr*16 + lq*4 + j)*64 + fc*16 + l15] = (half_t)p;
        }
#pragma unroll
    for (int fr = 0; fr < 2; ++fr)
#pragma unroll
      for (int j = 0; j < 4; ++j) {
        float t2 = psum[fr][j];
        t2 += __shfl_xor(t2, 1);
        t2 += __shfl_xor(t2, 2);
        t2 += __shfl_xor(t2, 4);
        t2 += __shfl_xor(t2, 8);
        lrow[fr][j] = lrow[fr][j]*corr[fr][j] + t2;
      }
#pragma unroll
    for (int fr = 0; fr < 2; ++fr)
#pragma unroll
      for (int fc = 0; fc < 5; ++fc)
#pragma unroll
        for (int j = 0; j < 4; ++j)
          oacc[fr][fc][j] *= corr[fr][j];

    asm volatile("s_waitcnt lgkmcnt(0)" ::: "memory");
    __builtin_amdgcn_s_barrier();
    __builtin_amdgcn_sched_barrier(0);

    const char* sPb = (const char*)sP;
    const char* sVb = (const char*)sV[cur];
    half8 pa[2][2];
#pragma unroll
    for (int fr = 0; fr < 2; ++fr) {
      int r = wv*32 + fr*16 + l15;
#pragma unroll
      for (int ks = 0; ks < 2; ++ks)
        pa[fr][ks] = *(const half8*)(sPb + r*128 + ks*64 + lq*16);
    }
#pragma unroll
    for (int fc = 0; fc < 5; ++fc)
#pragma unroll
      for (int ks = 0; ks < 2; ++ks) {
        half8 vb = *(const half8*)(sVb + (fc*16 + l15)*128 + ks*64 + lq*16);
#pragma unroll
        for (int fr = 0; fr < 2; ++fr)
          oacc[fr][fc] = MFMA32(pa[fr][ks], vb, oacc[fr][fc]);
      }

    asm volatile("s_waitcnt vmcnt(0) lgkmcnt(0)" ::: "memory");
    __builtin_amdgcn_s_barrier();
    __builtin_amdgcn_sched_barrier(0);
  }
#undef STAGE_KV

  const int img = gh >> 3, hh = gh & 7;
  half_t* og = og_ + ((size_t)img*1024 + qt*128)*640 + hh*80;
#pragma unroll
  for (int fr = 0; fr < 2; ++fr)
#pragma unroll
    for (int j = 0; j < 4; ++j) {
      int n = wv*32 + fr*16 + lq*4 + j;
      float inv = 1.f / lrow[fr][j];
#pragma unroll
      for (int fc = 0; fc < 5; ++fc)
        og[(size_t)n*640 + fc*16 + l15] = (half_t)(oacc[fr][fc][j] * inv);
    }
}

// ---------------- output projection GEMM: ring-3, single barrier/g, swizzled ----
__global__ __launch_bounds__(256) void k_proj(const half_t* __restrict__ oa,
                                              const half_t* __restrict__ wp,
                                              const float* __restrict__ bp,
                                              float* __restrict__ out) {
  __shared__ __align__(16) half_t sA[3][128*32];   // 8KB per slot
  __shared__ __align__(16) half_t sB[3][128*32];
  const int tid = threadIdx.x, lane = tid & 63, wv = tid >> 6;
  const int l15 = lane & 15, lq = lane >> 4, lq16 = lq*16;
  // XCD swizzle: 400 = 8 x 50; consecutive wg share (nt,img)
  const int id = blockIdx.x;
  const int wg = (id >> 3) + (id & 7)*50;
  const int mt = wg & 7;
  const int rest = wg >> 3;
  const int nt = rest % 5;
  const int img = rest / 5;
  const int bb = img / 5, mm = img - bb*5;
  const half_t* ag = oa + ((size_t)img*1024 + mt*128)*640;
  const half_t* bg = wp + (size_t)nt*128*640;
  const int wrow = (wv >> 1)*64, wcol = (wv & 1)*64;

  int asrc[2];
#pragma unroll
  for (int kk = 0; kk < 2; ++kk) {
    int idx = kk*256 + tid;
    int row = idx >> 2, sub = idx & 3;
    int ch = sub ^ ((row >> 1) & 3);
    asrc[kk] = row*640 + ch*8;
  }

#define STAGE_P(g, slot) do {                                                 \
    _Pragma("unroll")                                                         \
    for (int kk = 0; kk < 2; ++kk) {                                          \
      load16_lds(sA[slot] + (size_t)(kk*256 + wv*64)*8, ag + asrc[kk] + (g)*32); \
      load16_lds(sB[slot] + (size_t)(kk*256 + wv*64)*8, bg + asrc[kk] + (g)*32); \
    }                                                                         \
  } while (0)

  STAGE_P(0, 0);
  STAGE_P(1, 1);
  asm volatile("s_waitcnt vmcnt(4)" ::: "memory");   // slot0 ready, slot1 in flight
  asm volatile("s_barrier" ::: "memory");

  floatx4 acc[4][4] = {};
  int aoff[4], boff[4];
#pragma unroll
  for (int fr = 0; fr < 4; ++fr) {
    int r = wrow + fr*16 + l15;
    aoff[fr] = (r << 6) + (lq16 ^ (((r >> 1) & 3) << 4));
  }
#pragma unroll
  for (int fc = 0; fc < 4; ++fc) {
    int r = wcol + fc*16 + l15;
    boff[fc] = (r << 6) + (lq16 ^ (((r >> 1) & 3) << 4));
  }

  for (int g = 0; g < 20; ++g) {
    const int slot = g % 3;
    if (g + 2 < 20) STAGE_P(g + 2, (g + 2) % 3);
    const char* sAb = (const char*)sA[slot];
    const char* sBb = (const char*)sB[slot];
    half8 av[4], bw[4];
#pragma unroll
    for (int fr = 0; fr < 4; ++fr) av[fr] = *(const half8*)(sAb + aoff[fr]);
#pragma unroll
    for (int fc = 0; fc < 4; ++fc) bw[fc] = *(const half8*)(sBb + boff[fc]);
#pragma unroll
    for (int fr = 0; fr < 4; ++fr)
#pragma unroll
      for (int fc = 0; fc < 4; ++fc)
        acc[fr][fc] = MFMA32(av[fr], bw[fc], acc[fr][fc]);
    if (g < 19) {
      if (g + 2 < 20) asm volatile("s_waitcnt vmcnt(4)" ::: "memory");
      else            asm volatile("s_waitcnt vmcnt(0)" ::: "memory");
      asm volatile("s_waitcnt lgkmcnt(0)" ::: "memory");
      asm volatile("s_barrier" ::: "memory");
    }
  }
#undef STAGE_P

  float* og = out + ((size_t)bb*1024 + mt*128)*3200 + mm*640 + nt*128;
#pragma unroll
  for (int fc = 0; fc < 4; ++fc) {
    float bias = bp[nt*128 + wcol + fc*16 + l15];
#pragma unroll
    for (int fr = 0; fr < 4; ++fr)
#pragma unroll
      for (int j = 0; j < 4; ++j)
        og[(size_t)(wrow + fr*16 + lq*4 + j)*3200 + wcol + fc*16 + l15] = acc[fr][fc][j] + bias;
  }
}

extern "C" void kernel_launch(void* const* d_in, const int* in_sizes, int n_in,
                              void* d_out, int out_size, void* d_ws, size_t ws_size,
                              hipStream_t stream) {
  const float* x  = (const float*)d_in[0];
  const float* wq = (const float*)d_in[1];
  const float* bq = (const float*)d_in[2];
  const float* wk = (const float*)d_in[3];
  const float* bk = (const float*)d_in[4];
  const float* wv = (const float*)d_in[5];
  const float* bv = (const float*)d_in[6];
  const float* wp = (const float*)d_in[7];
  const float* bp = (const float*)d_in[8];
  float* out = (float*)d_out;

  half_t* xpad = (half_t*)d_ws;
  half_t* wr2  = xpad + XPAD_ELEMS;
  half_t* wp16 = wr2 + WR_ELEMS;
  half_t* q    = wp16 + WP_ELEMS;
  half_t* k    = q + QKV_ELEMS;
  half_t* v    = k + QKV_ELEMS;
  half_t* oa   = v + QKV_ELEMS;

  (void)hipMemsetAsync(xpad, 0, (size_t)XPAD_ELEMS*sizeof(half_t), stream);
  k_convert_x<<<320, 256, 0, stream>>>(x, xpad);
  k_convert_w<<<dim3(640, 4), 256, 0, stream>>>(wq, wk, wv, wp, wr2, wp16);
  k_conv<<<480, 512, 0, stream>>>(xpad, wr2, bq, bk, bv, q, k, v);
  k_attn<<<640, 256, 0, stream>>>(q, k, v, oa);
  k_proj<<<400, 256, 0, stream>>>(oa, wp16, bp, out);
}